// Round 1
// baseline (341.966 us; speedup 1.0000x reference)
//
#include <hip/hip_runtime.h>

#define S_DIM 128
#define I_DIM 384
#define IN_DIM 256
#define PD 32
#define ODIM 128

typedef __attribute__((ext_vector_type(8))) __bf16 bf16x8;
typedef __attribute__((ext_vector_type(4))) float f32x4;

#define MFMA16(a, b, c) __builtin_amdgcn_mfma_f32_16x16x32_bf16((a), (b), (c), 0, 0, 0)

__device__ inline unsigned short f2bf(float f) {
    unsigned int u = __builtin_bit_cast(unsigned int, f);
    unsigned int r = (u + 0x7FFFu + ((u >> 16) & 1u)) >> 16;
    return (unsigned short)r;
}

// ---------------- prep: cast/transpose weights to bf16 ----------------
__global__ void prep_cast(const float* __restrict__ Wp, const float* __restrict__ W2,
                          unsigned short* __restrict__ WpT, unsigned short* __restrict__ W2t) {
    int t = blockIdx.x * 256 + threadIdx.x;
    if (t < 64 * 256) {
        int f = t >> 8, k = t & 255;
        WpT[t] = f2bf(Wp[k * 64 + f]);
    }
    if (t < 128 * 1024) {
        int f = t >> 10, de = t & 1023;
        int e = de >> 5, d = de & 31;
        W2t[t] = f2bf(W2[(d * 32 + e) * 128 + f]);
    }
}

// ---------------- norm: gram of mask -> store INVERSE ----------------
__global__ void norm_kernel(const float* __restrict__ mask, float* __restrict__ invn) {
    __shared__ float mi[S_DIM][16];
    __shared__ float mj[S_DIM][16];
    int t = threadIdx.x;
    int i0 = blockIdx.y * 16, j0 = blockIdx.x * 16;
    for (int p = 0; p < 8; ++p) {
        int s = p * 16 + (t >> 4);
        int c = t & 15;
        mi[s][c] = mask[s * I_DIM + i0 + c];
        mj[s][c] = mask[s * I_DIM + j0 + c];
    }
    __syncthreads();
    int ii = t >> 4, jj = t & 15;
    float acc = 0.f;
#pragma unroll 8
    for (int s = 0; s < S_DIM; ++s) acc += mi[s][ii] * mj[s][jj];
    invn[(i0 + ii) * I_DIM + (j0 + jj)] = 1.0f / (acc + 0.001f);
}

// ---------------- LN + projection (bf16 MFMA), i-major for coalesced T-store ----
__global__ __launch_bounds__(256, 2) void ln_proj(const float* __restrict__ x,
                                                  const float* __restrict__ mask,
                                                  const float* __restrict__ bias,
                                                  const unsigned short* __restrict__ WpT_g,
                                                  unsigned short* __restrict__ lT,
                                                  unsigned short* __restrict__ rT) {
    __shared__ unsigned short xsh[64 * 264];
    __shared__ unsigned short wpT[64 * 264];
    int t = threadIdx.x;
    int w = t >> 6, lane = t & 63;
    int i = blockIdx.x >> 1;
    int s0 = (blockIdx.x & 1) * 64;

    {
        int f = t >> 2, kq = (t & 3) * 64;
#pragma unroll
        for (int p = 0; p < 8; ++p) {
            int k = kq + p * 8;
            *(uint4*)&wpT[f * 264 + k] = *(const uint4*)&WpT_g[f * 256 + k];
        }
    }

    float4 vbuf[4];
#pragma unroll
    for (int p = 0; p < 4; ++p)
        vbuf[p] = *(const float4*)(x + ((size_t)(s0 + w * 16 + p) * I_DIM + i) * IN_DIM + lane * 4);

    for (int it = 0; it < 16; ++it) {
        float4 v = vbuf[it & 3];
        if (it + 4 < 16)
            vbuf[it & 3] = *(const float4*)(x + ((size_t)(s0 + w * 16 + it + 4) * I_DIM + i) * IN_DIM + lane * 4);
        float s1 = v.x + v.y + v.z + v.w;
        float s2 = v.x * v.x + v.y * v.y + v.z * v.z + v.w * v.w;
#pragma unroll
        for (int off = 32; off >= 1; off >>= 1) {
            s1 += __shfl_xor(s1, off);
            s2 += __shfl_xor(s2, off);
        }
        float mu = s1 * (1.f / 256.f);
        float var = s2 * (1.f / 256.f) - mu * mu;
        float rs = rsqrtf(var + 1e-5f);
        unsigned int h0 = f2bf((v.x - mu) * rs);
        unsigned int h1 = f2bf((v.y - mu) * rs);
        unsigned int h2 = f2bf((v.z - mu) * rs);
        unsigned int h3 = f2bf((v.w - mu) * rs);
        uint2 pk;
        pk.x = h0 | (h1 << 16);
        pk.y = h2 | (h3 << 16);
        *(uint2*)&xsh[(w * 16 + it) * 264 + lane * 4] = pk;
    }
    __syncthreads();

    int l15 = lane & 15, q = lane >> 4;
    f32x4 acc[4];
#pragma unroll
    for (int nt = 0; nt < 4; ++nt) acc[nt] = (f32x4){0.f, 0.f, 0.f, 0.f};

    for (int k0 = 0; k0 < 256; k0 += 32) {
        bf16x8 a = *(bf16x8*)&xsh[(w * 16 + l15) * 264 + k0 + q * 8];
#pragma unroll
        for (int nt = 0; nt < 4; ++nt) {
            bf16x8 b = *(bf16x8*)&wpT[(nt * 16 + l15) * 264 + k0 + q * 8];
            acc[nt] = MFMA16(a, b, acc[nt]);
        }
    }

    float mval[4];
#pragma unroll
    for (int reg = 0; reg < 4; ++reg)
        mval[reg] = mask[(size_t)(s0 + w * 16 + q * 4 + reg) * I_DIM + i];

    __syncthreads();
    unsigned short* trsh = xsh;

#pragma unroll
    for (int nt = 0; nt < 4; ++nt) {
        int f = nt * 16 + l15;
        float bv = bias[f];
        unsigned int lo = (unsigned int)f2bf((acc[nt][0] + bv) * mval[0]) |
                          ((unsigned int)f2bf((acc[nt][1] + bv) * mval[1]) << 16);
        unsigned int hi = (unsigned int)f2bf((acc[nt][2] + bv) * mval[2]) |
                          ((unsigned int)f2bf((acc[nt][3] + bv) * mval[3]) << 16);
        uint2 pk; pk.x = lo; pk.y = hi;
        *(uint2*)&trsh[f * 72 + w * 16 + q * 4] = pk;
    }
    __syncthreads();

    {
        int fr = t >> 2, so = (t & 3) * 16;
        unsigned short* dst = ((fr < 32) ? lT : rT) + ((size_t)(i * 32 + (fr & 31)) * 128 + s0 + so);
        *(uint4*)dst = *(uint4*)&trsh[fr * 72 + so];
        *(uint4*)(dst + 8) = *(uint4*)&trsh[fr * 72 + so + 8];
    }
}

// ---------------- FUSED outer + contract ----------------
// Block = 8 i's x 4 j's (32 pairs). grid (96, 48), 256 threads (4 waves).
// Phase 1: outer GEMM M=256 (8i*32d), N=128 (4j*32e), K=128(s).
//          wave (wm,wn): rows wm*128 + mt*16 (mt 0..7), cols wn*64 + nt*16 (nt 0..3).
// Phase 2: G[pair][k=e*32+d] bf16 in LDS (64 KB), XOR swizzle byte ^= (pair&7)<<4.
// Phase 3: contract M=32 pairs, N=128 f, K=1024; k split 4 ways across waves
//          (each G byte read once; W2t read once per block).
// Phase 4: cross-wave f32 reduction in LDS, coalesced epilogue store.
__global__ __launch_bounds__(256, 2) void fused_kernel(const unsigned short* __restrict__ lT,
                                                       const unsigned short* __restrict__ rT,
                                                       const unsigned short* __restrict__ W2t,
                                                       const float* __restrict__ invn,
                                                       const float* __restrict__ out_bias,
                                                       float* __restrict__ out) {
    __shared__ unsigned short sh[32768];   // 64 KB: rT stage -> G tile -> f32 partials
    int t = threadIdx.x;
    int w = t >> 6, lane = t & 63, l15 = lane & 15, q = lane >> 4;
    int bx = blockIdx.x;   // j-block (4 j)
    int by = blockIdx.y;   // i-block (8 i)
    int wm = w >> 1, wn = w & 1;
    char* shb = (char*)sh;

    // ---- stage rT tile: rows bx*128..+127 (j*32+e), cols s 0..127, pitch 136
    {
        int m0 = t >> 3, c0 = (t & 7) * 8;
        const unsigned short* rbase = rT + (size_t)(bx * 128 + m0) * 128 + c0;
#pragma unroll
        for (int p = 0; p < 4; ++p) {
            *(uint4*)&sh[(m0 + p * 32) * 136 + c0] = *(const uint4*)(rbase + (size_t)p * 32 * 128);
            *(uint4*)&sh[(m0 + p * 32) * 136 + c0 + 64] = *(const uint4*)(rbase + (size_t)p * 32 * 128 + 64);
        }
    }
    __syncthreads();

    // ---- phase 1: outer GEMM
    f32x4 acc[8][4];
#pragma unroll
    for (int mt = 0; mt < 8; ++mt)
#pragma unroll
        for (int nt = 0; nt < 4; ++nt) acc[mt][nt] = (f32x4){0.f, 0.f, 0.f, 0.f};

    const unsigned short* lbase = lT + (size_t)(by * 256 + wm * 128 + l15) * 128 + q * 8;

    bf16x8 a[8];
#pragma unroll
    for (int mt = 0; mt < 8; ++mt) a[mt] = *(const bf16x8*)(lbase + mt * 2048);

#pragma unroll
    for (int k0 = 0; k0 < 4; ++k0) {
        bf16x8 na[8];
        if (k0 < 3) {
#pragma unroll
            for (int mt = 0; mt < 8; ++mt)
                na[mt] = *(const bf16x8*)(lbase + mt * 2048 + (k0 + 1) * 32);
        }
#pragma unroll
        for (int nt = 0; nt < 4; ++nt) {
            bf16x8 b = *(bf16x8*)&sh[(wn * 64 + nt * 16 + l15) * 136 + k0 * 32 + q * 8];
#pragma unroll
            for (int mt = 0; mt < 8; ++mt)
                acc[mt][nt] = MFMA16(a[mt], b, acc[mt][nt]);
        }
        if (k0 < 3) {
#pragma unroll
            for (int mt = 0; mt < 8; ++mt) a[mt] = na[mt];
        }
    }
    __syncthreads();

    // ---- phase 2: write G[pair][k] bf16 into LDS with XOR swizzle
#pragma unroll
    for (int mt = 0; mt < 8; ++mt) {
        int i_loc = wm * 4 + (mt >> 1);
        int dbase = (mt & 1) * 16 + q * 4;
#pragma unroll
        for (int nt = 0; nt < 4; ++nt) {
            int j_loc = wn * 2 + (nt >> 1);
            int e = (nt & 1) * 16 + l15;
            int pair = i_loc * 4 + j_loc;
            int kk = e * 32 + dbase;
            unsigned int lo = (unsigned int)f2bf(acc[mt][nt][0]) | ((unsigned int)f2bf(acc[mt][nt][1]) << 16);
            unsigned int hi = (unsigned int)f2bf(acc[mt][nt][2]) | ((unsigned int)f2bf(acc[mt][nt][3]) << 16);
            uint2 pk; pk.x = lo; pk.y = hi;
            *(uint2*)(shb + pair * 2048 + ((kk * 2) ^ ((pair & 7) << 4))) = pk;
        }
    }
    __syncthreads();

    // ---- phase 3: contract, wave w owns k0 = w*8 .. w*8+7 (k = k0*32..)
    f32x4 acc3[2][8];
#pragma unroll
    for (int mt = 0; mt < 2; ++mt)
#pragma unroll
        for (int nt = 0; nt < 8; ++nt) acc3[mt][nt] = (f32x4){0.f, 0.f, 0.f, 0.f};

    const unsigned short* wbase = W2t + (size_t)l15 * 1024 + q * 8;

    for (int kq = 0; kq < 8; ++kq) {
        int k0 = w * 8 + kq;
        bf16x8 bfr[8];
#pragma unroll
        for (int nt = 0; nt < 8; ++nt)
            bfr[nt] = *(const bf16x8*)(wbase + (size_t)nt * 16384 + k0 * 32);
        int swz = ((k0 * 64 + q * 16) ^ ((l15 & 7) << 4));
        bf16x8 a0 = *(bf16x8*)(shb + l15 * 2048 + swz);
        bf16x8 a1 = *(bf16x8*)(shb + (16 + l15) * 2048 + swz);
#pragma unroll
        for (int nt = 0; nt < 8; ++nt) {
            acc3[0][nt] = MFMA16(a0, bfr[nt], acc3[0][nt]);
            acc3[1][nt] = MFMA16(a1, bfr[nt], acc3[1][nt]);
        }
    }
    __syncthreads();

    // ---- phase 4a: store f32 partials: shf[w][pair][f ^ bank-swz]
    float* shf = (float*)sh;
#pragma unroll
    for (int mt3 = 0; mt3 < 2; ++mt3) {
#pragma unroll
        for (int nt = 0; nt < 8; ++nt) {
#pragma unroll
            for (int reg = 0; reg < 4; ++reg) {
                int pair = mt3 * 16 + q * 4 + reg;
                int f = nt * 16 + l15;
                shf[w * 4096 + pair * 128 + (f ^ (((pair >> 2) & 1) << 4))] = acc3[mt3][nt][reg];
            }
        }
    }
    __syncthreads();

    // ---- phase 4b: reduce over 4 waves + epilogue (coalesced, 128 f per row)
#pragma unroll 4
    for (int it = 0; it < 16; ++it) {
        int v = it * 256 + t;
        int pair = v >> 7, f = v & 127;
        int idx = pair * 128 + (f ^ (((pair >> 2) & 1) << 4));
        float s = shf[idx] + shf[4096 + idx] + shf[8192 + idx] + shf[12288 + idx];
        int gi = by * 8 + (pair >> 2);
        int gj = bx * 4 + (pair & 3);
        out[((size_t)gi * I_DIM + gj) * 128 + f] = (s + out_bias[f]) * invn[gi * I_DIM + gj];
    }
}

extern "C" void kernel_launch(void* const* d_in, const int* in_sizes, int n_in,
                              void* d_out, int out_size, void* d_ws, size_t ws_size,
                              hipStream_t stream) {
    const float* node = (const float*)d_in[0];
    const float* mask = (const float*)d_in[1];
    const float* Wp   = (const float*)d_in[2];
    const float* bp   = (const float*)d_in[3];
    const float* W2   = (const float*)d_in[4];
    const float* bo   = (const float*)d_in[5];
    float* out = (float*)d_out;

    char* ws = (char*)d_ws;
    unsigned short* lT  = (unsigned short*)(ws);             // 3,145,728
    unsigned short* rT  = (unsigned short*)(ws + 3145728);   // 3,145,728
    unsigned short* W2t = (unsigned short*)(ws + 6291456);   // 262,144
    unsigned short* WpT = (unsigned short*)(ws + 6553600);   // 32,768
    float*          inv = (float*)(ws + 6586368);            // 589,824

    hipLaunchKernelGGL(prep_cast, dim3(512), dim3(256), 0, stream, Wp, W2, WpT, W2t);
    hipLaunchKernelGGL(norm_kernel, dim3(24, 24), dim3(256), 0, stream, mask, inv);
    hipLaunchKernelGGL(ln_proj, dim3(768), dim3(256), 0, stream, node, mask, bp, WpT, lT, rT);
    hipLaunchKernelGGL(fused_kernel, dim3(96, 48), dim3(256), 0, stream,
                       lT, rT, W2t, inv, bo, out);
}

// Round 2
// 335.340 us; speedup vs baseline: 1.0198x; 1.0198x over previous
//
#include <hip/hip_runtime.h>

#define S_DIM 128
#define I_DIM 384
#define IN_DIM 256
#define PD 32
#define ODIM 128

typedef __attribute__((ext_vector_type(8))) __bf16 bf16x8;
typedef __attribute__((ext_vector_type(4))) float f32x4;

#define MFMA16(a, b, c) __builtin_amdgcn_mfma_f32_16x16x32_bf16((a), (b), (c), 0, 0, 0)

__device__ inline unsigned short f2bf(float f) {
    unsigned int u = __builtin_bit_cast(unsigned int, f);
    unsigned int r = (u + 0x7FFFu + ((u >> 16) & 1u)) >> 16;
    return (unsigned short)r;
}

// ---------------- prep: cast/transpose weights to bf16 ----------------
__global__ void prep_cast(const float* __restrict__ Wp, const float* __restrict__ W2,
                          unsigned short* __restrict__ WpT, unsigned short* __restrict__ W2t) {
    int t = blockIdx.x * 256 + threadIdx.x;
    if (t < 64 * 256) {
        int f = t >> 8, k = t & 255;
        WpT[t] = f2bf(Wp[k * 64 + f]);
    }
    if (t < 128 * 1024) {
        int f = t >> 10, de = t & 1023;
        int e = de >> 5, d = de & 31;
        W2t[t] = f2bf(W2[(d * 32 + e) * 128 + f]);
    }
}

// ---------------- norm: gram of mask -> store INVERSE ----------------
__global__ void norm_kernel(const float* __restrict__ mask, float* __restrict__ invn) {
    __shared__ float mi[S_DIM][16];
    __shared__ float mj[S_DIM][16];
    int t = threadIdx.x;
    int i0 = blockIdx.y * 16, j0 = blockIdx.x * 16;
    for (int p = 0; p < 8; ++p) {
        int s = p * 16 + (t >> 4);
        int c = t & 15;
        mi[s][c] = mask[s * I_DIM + i0 + c];
        mj[s][c] = mask[s * I_DIM + j0 + c];
    }
    __syncthreads();
    int ii = t >> 4, jj = t & 15;
    float acc = 0.f;
#pragma unroll 8
    for (int s = 0; s < S_DIM; ++s) acc += mi[s][ii] * mj[s][jj];
    invn[(i0 + ii) * I_DIM + (j0 + jj)] = 1.0f / (acc + 0.001f);
}

// ---------------- LN + projection (bf16 MFMA), i-major for coalesced T-store ----
// WpT read direct from global (32 KB, L1/L2-hot) -> LDS 33.8 KB -> 4 blocks/CU.
__global__ __launch_bounds__(256, 4) void ln_proj(const float* __restrict__ x,
                                                  const float* __restrict__ mask,
                                                  const float* __restrict__ bias,
                                                  const unsigned short* __restrict__ WpT_g,
                                                  unsigned short* __restrict__ lT,
                                                  unsigned short* __restrict__ rT) {
    __shared__ unsigned short xsh[64 * 264];
    int t = threadIdx.x;
    int w = t >> 6, lane = t & 63;
    int i = blockIdx.x >> 1;
    int s0 = (blockIdx.x & 1) * 64;

    float4 vbuf[4];
#pragma unroll
    for (int p = 0; p < 4; ++p)
        vbuf[p] = *(const float4*)(x + ((size_t)(s0 + w * 16 + p) * I_DIM + i) * IN_DIM + lane * 4);

    for (int it = 0; it < 16; ++it) {
        float4 v = vbuf[it & 3];
        if (it + 4 < 16)
            vbuf[it & 3] = *(const float4*)(x + ((size_t)(s0 + w * 16 + it + 4) * I_DIM + i) * IN_DIM + lane * 4);
        float s1 = v.x + v.y + v.z + v.w;
        float s2 = v.x * v.x + v.y * v.y + v.z * v.z + v.w * v.w;
#pragma unroll
        for (int off = 32; off >= 1; off >>= 1) {
            s1 += __shfl_xor(s1, off);
            s2 += __shfl_xor(s2, off);
        }
        float mu = s1 * (1.f / 256.f);
        float var = s2 * (1.f / 256.f) - mu * mu;
        float rs = rsqrtf(var + 1e-5f);
        unsigned int h0 = f2bf((v.x - mu) * rs);
        unsigned int h1 = f2bf((v.y - mu) * rs);
        unsigned int h2 = f2bf((v.z - mu) * rs);
        unsigned int h3 = f2bf((v.w - mu) * rs);
        uint2 pk;
        pk.x = h0 | (h1 << 16);
        pk.y = h2 | (h3 << 16);
        *(uint2*)&xsh[(w * 16 + it) * 264 + lane * 4] = pk;
    }
    __syncthreads();

    int l15 = lane & 15, q = lane >> 4;
    f32x4 acc[4];
#pragma unroll
    for (int nt = 0; nt < 4; ++nt) acc[nt] = (f32x4){0.f, 0.f, 0.f, 0.f};

    for (int k0 = 0; k0 < 256; k0 += 32) {
        bf16x8 a = *(bf16x8*)&xsh[(w * 16 + l15) * 264 + k0 + q * 8];
#pragma unroll
        for (int nt = 0; nt < 4; ++nt) {
            bf16x8 b = *(const bf16x8*)&WpT_g[(nt * 16 + l15) * 256 + k0 + q * 8];
            acc[nt] = MFMA16(a, b, acc[nt]);
        }
    }

    float mval[4];
#pragma unroll
    for (int reg = 0; reg < 4; ++reg)
        mval[reg] = mask[(size_t)(s0 + w * 16 + q * 4 + reg) * I_DIM + i];

    __syncthreads();
    unsigned short* trsh = xsh;

#pragma unroll
    for (int nt = 0; nt < 4; ++nt) {
        int f = nt * 16 + l15;
        float bv = bias[f];
        unsigned int lo = (unsigned int)f2bf((acc[nt][0] + bv) * mval[0]) |
                          ((unsigned int)f2bf((acc[nt][1] + bv) * mval[1]) << 16);
        unsigned int hi = (unsigned int)f2bf((acc[nt][2] + bv) * mval[2]) |
                          ((unsigned int)f2bf((acc[nt][3] + bv) * mval[3]) << 16);
        uint2 pk; pk.x = lo; pk.y = hi;
        *(uint2*)&trsh[f * 72 + w * 16 + q * 4] = pk;
    }
    __syncthreads();

    {
        int fr = t >> 2, so = (t & 3) * 16;
        unsigned short* dst = ((fr < 32) ? lT : rT) + ((size_t)(i * 32 + (fr & 31)) * 128 + s0 + so);
        *(uint4*)dst = *(uint4*)&trsh[fr * 72 + so];
        *(uint4*)(dst + 8) = *(uint4*)&trsh[fr * 72 + so + 8];
    }
}

// ---------------- FUSED outer + contract, 512 threads (8 waves) ----------------
// Block = 8 i's x 4 j's (32 pairs). grid (96, 48).
// Phase 1: outer GEMM M=256 (8i*32d), N=128 (4j*32e), K=128(s).
//          wave (wm=w>>1 in 0..3, wn=w&1): tile 64x64, acc[4][4].
// Phase 2: G[pair][k=e*32+d] bf16 in LDS (64 KB),
//          byte addr = pair*2048 + ((e*64+d*2) ^ ((e&7)<<4) ^ ((pair&7)<<4)).
//          The ^(e&7) term spreads phase-2 store lanes (e varies per lane) across
//          bank slots; phase-3 reads have e=k0 uniform so their spread is unchanged.
// Phase 3: f-split: wave w owns f = w*16..+15, all 32 pairs, full K=1024.
//          No cross-wave reduction. W2t prefetched across the barrier.
__global__ __launch_bounds__(512, 4) void fused_kernel(const unsigned short* __restrict__ lT,
                                                       const unsigned short* __restrict__ rT,
                                                       const unsigned short* __restrict__ W2t,
                                                       const float* __restrict__ invn,
                                                       const float* __restrict__ out_bias,
                                                       float* __restrict__ out) {
    __shared__ unsigned short sh[32768];   // 64 KB: rT stage (34.8 KB) -> G tile (64 KB)
    char* shb = (char*)sh;
    int t = threadIdx.x;
    int w = t >> 6, lane = t & 63, l15 = lane & 15, q = lane >> 4;
    int bx = blockIdx.x;   // j-block (4 j)
    int by = blockIdx.y;   // i-block (8 i)
    int wm = w >> 1, wn = w & 1;

    // ---- stage rT tile: rows bx*128..+127 (j*32+e), cols s 0..127, pitch 136
    {
        int row = t >> 2, c0 = (t & 3) * 32;
        const unsigned short* rbase = rT + (size_t)(bx * 128 + row) * 128 + c0;
        uint4 v0 = ((const uint4*)rbase)[0];
        uint4 v1 = ((const uint4*)rbase)[1];
        uint4 v2 = ((const uint4*)rbase)[2];
        uint4 v3 = ((const uint4*)rbase)[3];
        *(uint4*)&sh[row * 136 + c0] = v0;
        *(uint4*)&sh[row * 136 + c0 + 8] = v1;
        *(uint4*)&sh[row * 136 + c0 + 16] = v2;
        *(uint4*)&sh[row * 136 + c0 + 24] = v3;
    }

    // phase-1 A fragments for k0=0, issued before the barrier (global, independent)
    const unsigned short* lbase = lT + (size_t)(by * 256 + wm * 64 + l15) * 128 + q * 8;
    bf16x8 a0_ = *(const bf16x8*)(lbase);
    bf16x8 a1_ = *(const bf16x8*)(lbase + 2048);
    bf16x8 a2_ = *(const bf16x8*)(lbase + 4096);
    bf16x8 a3_ = *(const bf16x8*)(lbase + 6144);
    __syncthreads();

    // ---- phase 1: outer GEMM, wave tile 64x64
    f32x4 acc[4][4];
#pragma unroll
    for (int mt = 0; mt < 4; ++mt)
#pragma unroll
        for (int nt = 0; nt < 4; ++nt) acc[mt][nt] = (f32x4){0.f, 0.f, 0.f, 0.f};

#pragma unroll
    for (int k0 = 0; k0 < 4; ++k0) {
        bf16x8 a[4];
        if (k0 == 0) {
            a[0] = a0_; a[1] = a1_; a[2] = a2_; a[3] = a3_;
        } else {
#pragma unroll
            for (int mt = 0; mt < 4; ++mt)
                a[mt] = *(const bf16x8*)(lbase + mt * 2048 + k0 * 32);
        }
#pragma unroll
        for (int nt = 0; nt < 4; ++nt) {
            bf16x8 b = *(bf16x8*)&sh[(wn * 64 + nt * 16 + l15) * 136 + k0 * 32 + q * 8];
#pragma unroll
            for (int mt = 0; mt < 4; ++mt)
                acc[mt][nt] = MFMA16(a[mt], b, acc[mt][nt]);
        }
    }
    __syncthreads();

    // ---- phase 2: write G[pair][k] bf16 into LDS (swizzled)
#pragma unroll
    for (int mt = 0; mt < 4; ++mt) {
        int i_loc = wm * 2 + (mt >> 1);
        int dbase2 = ((mt & 1) * 16 + q * 4) * 2;
#pragma unroll
        for (int nt = 0; nt < 4; ++nt) {
            int pair = i_loc * 4 + wn * 2 + (nt >> 1);
            int e = (nt & 1) * 16 + l15;
            unsigned int lo = (unsigned int)f2bf(acc[mt][nt][0]) | ((unsigned int)f2bf(acc[mt][nt][1]) << 16);
            unsigned int hi = (unsigned int)f2bf(acc[mt][nt][2]) | ((unsigned int)f2bf(acc[mt][nt][3]) << 16);
            uint2 pk; pk.x = lo; pk.y = hi;
            *(uint2*)(shb + pair * 2048 + ((e * 64 + dbase2) ^ ((e & 7) << 4) ^ ((pair & 7) << 4))) = pk;
        }
    }

    // prefetch first 4 W2t fragments across the barrier
    const unsigned short* wrow = W2t + (size_t)(w * 16 + l15) * 1024 + q * 8;
    bf16x8 bp0 = *(const bf16x8*)(wrow);
    bf16x8 bp1 = *(const bf16x8*)(wrow + 32);
    bf16x8 bp2 = *(const bf16x8*)(wrow + 64);
    bf16x8 bp3 = *(const bf16x8*)(wrow + 96);
    __syncthreads();

    // ---- phase 3: contract; wave w owns f = w*16 + l15, all 32 pairs, K=1024
    f32x4 acc3[2];
    acc3[0] = (f32x4){0.f, 0.f, 0.f, 0.f};
    acc3[1] = (f32x4){0.f, 0.f, 0.f, 0.f};
    char* gbase0 = shb + l15 * 2048;
    char* gbase1 = shb + (16 + l15) * 2048;
    int sx = (l15 & 7) << 4;

#pragma unroll
    for (int k0 = 0; k0 < 32; ++k0) {
        bf16x8 b;
        if (k0 == 0) b = bp0;
        else if (k0 == 1) b = bp1;
        else if (k0 == 2) b = bp2;
        else if (k0 == 3) b = bp3;
        else b = *(const bf16x8*)(wrow + k0 * 32);
        int off = ((k0 * 64 + q * 16) ^ ((k0 & 7) << 4)) ^ sx;
        bf16x8 a0 = *(bf16x8*)(gbase0 + off);
        bf16x8 a1 = *(bf16x8*)(gbase1 + off);
        acc3[0] = MFMA16(a0, b, acc3[0]);
        acc3[1] = MFMA16(a1, b, acc3[1]);
    }

    // ---- epilogue: direct store from regs (no cross-wave reduction)
    float bv = out_bias[w * 16 + l15];
#pragma unroll
    for (int mt3 = 0; mt3 < 2; ++mt3) {
#pragma unroll
        for (int reg = 0; reg < 4; ++reg) {
            int pair = mt3 * 16 + q * 4 + reg;
            int gi = by * 8 + (pair >> 2);
            int gj = bx * 4 + (pair & 3);
            float vinv = invn[gi * I_DIM + gj];
            out[((size_t)gi * I_DIM + gj) * 128 + w * 16 + l15] = (acc3[mt3][reg] + bv) * vinv;
        }
    }
}

extern "C" void kernel_launch(void* const* d_in, const int* in_sizes, int n_in,
                              void* d_out, int out_size, void* d_ws, size_t ws_size,
                              hipStream_t stream) {
    const float* node = (const float*)d_in[0];
    const float* mask = (const float*)d_in[1];
    const float* Wp   = (const float*)d_in[2];
    const float* bp   = (const float*)d_in[3];
    const float* W2   = (const float*)d_in[4];
    const float* bo   = (const float*)d_in[5];
    float* out = (float*)d_out;

    char* ws = (char*)d_ws;
    unsigned short* lT  = (unsigned short*)(ws);             // 3,145,728
    unsigned short* rT  = (unsigned short*)(ws + 3145728);   // 3,145,728
    unsigned short* W2t = (unsigned short*)(ws + 6291456);   // 262,144
    unsigned short* WpT = (unsigned short*)(ws + 6553600);   // 32,768
    float*          inv = (float*)(ws + 6586368);            // 589,824

    hipLaunchKernelGGL(prep_cast, dim3(512), dim3(256), 0, stream, Wp, W2, WpT, W2t);
    hipLaunchKernelGGL(norm_kernel, dim3(24, 24), dim3(256), 0, stream, mask, inv);
    hipLaunchKernelGGL(ln_proj, dim3(768), dim3(256), 0, stream, node, mask, bp, WpT, lT, rT);
    hipLaunchKernelGGL(fused_kernel, dim3(96, 48), dim3(512), 0, stream,
                       lT, rT, W2t, inv, bo, out);
}

// Round 4
// 269.301 us; speedup vs baseline: 1.2698x; 1.2452x over previous
//
#include <hip/hip_runtime.h>

#define S_DIM 128
#define I_DIM 384
#define IN_DIM 256
#define PD 32
#define ODIM 128

typedef __attribute__((ext_vector_type(8))) __bf16 bf16x8;
typedef __attribute__((ext_vector_type(4))) float f32x4;

#define MFMA16(a, b, c) __builtin_amdgcn_mfma_f32_16x16x32_bf16((a), (b), (c), 0, 0, 0)

__device__ inline unsigned short f2bf(float f) {
    unsigned int u = __builtin_bit_cast(unsigned int, f);
    unsigned int r = (u + 0x7FFFu + ((u >> 16) & 1u)) >> 16;
    return (unsigned short)r;
}

// ---------------- prep: cast/transpose weights to bf16 ----------------
// W2s is SLICE-MAJOR: W2s[e][f][d]  (32 x 128 x 32), so one k-slice (e) of all
// 128 f-rows is 8 KB contiguous -> coalesced global_load_lds streaming in phase 3.
__global__ void prep_cast(const float* __restrict__ Wp, const float* __restrict__ W2,
                          unsigned short* __restrict__ WpT, unsigned short* __restrict__ W2s) {
    int t = blockIdx.x * 256 + threadIdx.x;
    if (t < 64 * 256) {
        int f = t >> 8, k = t & 255;
        WpT[t] = f2bf(Wp[k * 64 + f]);
    }
    if (t < 128 * 1024) {
        int e = t >> 12;
        int f = (t >> 5) & 127;
        int d = t & 31;
        W2s[t] = f2bf(W2[(d * 32 + e) * 128 + f]);
    }
}

// ---------------- norm: gram of mask -> store INVERSE ----------------
__global__ void norm_kernel(const float* __restrict__ mask, float* __restrict__ invn) {
    __shared__ float mi[S_DIM][16];
    __shared__ float mj[S_DIM][16];
    int t = threadIdx.x;
    int i0 = blockIdx.y * 16, j0 = blockIdx.x * 16;
    for (int p = 0; p < 8; ++p) {
        int s = p * 16 + (t >> 4);
        int c = t & 15;
        mi[s][c] = mask[s * I_DIM + i0 + c];
        mj[s][c] = mask[s * I_DIM + j0 + c];
    }
    __syncthreads();
    int ii = t >> 4, jj = t & 15;
    float acc = 0.f;
#pragma unroll 8
    for (int s = 0; s < S_DIM; ++s) acc += mi[s][ii] * mj[s][jj];
    invn[(i0 + ii) * I_DIM + (j0 + jj)] = 1.0f / (acc + 0.001f);
}

// ---------------- LN + projection (bf16 MFMA), i-major for coalesced T-store ----
__global__ __launch_bounds__(256, 4) void ln_proj(const float* __restrict__ x,
                                                  const float* __restrict__ mask,
                                                  const float* __restrict__ bias,
                                                  const unsigned short* __restrict__ WpT_g,
                                                  unsigned short* __restrict__ lT,
                                                  unsigned short* __restrict__ rT) {
    __shared__ unsigned short xsh[64 * 264];
    int t = threadIdx.x;
    int w = t >> 6, lane = t & 63;
    int i = blockIdx.x >> 1;
    int s0 = (blockIdx.x & 1) * 64;

    float4 vbuf[4];
#pragma unroll
    for (int p = 0; p < 4; ++p)
        vbuf[p] = *(const float4*)(x + ((size_t)(s0 + w * 16 + p) * I_DIM + i) * IN_DIM + lane * 4);

    for (int it = 0; it < 16; ++it) {
        float4 v = vbuf[it & 3];
        if (it + 4 < 16)
            vbuf[it & 3] = *(const float4*)(x + ((size_t)(s0 + w * 16 + it + 4) * I_DIM + i) * IN_DIM + lane * 4);
        float s1 = v.x + v.y + v.z + v.w;
        float s2 = v.x * v.x + v.y * v.y + v.z * v.z + v.w * v.w;
#pragma unroll
        for (int off = 32; off >= 1; off >>= 1) {
            s1 += __shfl_xor(s1, off);
            s2 += __shfl_xor(s2, off);
        }
        float mu = s1 * (1.f / 256.f);
        float var = s2 * (1.f / 256.f) - mu * mu;
        float rs = rsqrtf(var + 1e-5f);
        unsigned int h0 = f2bf((v.x - mu) * rs);
        unsigned int h1 = f2bf((v.y - mu) * rs);
        unsigned int h2 = f2bf((v.z - mu) * rs);
        unsigned int h3 = f2bf((v.w - mu) * rs);
        uint2 pk;
        pk.x = h0 | (h1 << 16);
        pk.y = h2 | (h3 << 16);
        *(uint2*)&xsh[(w * 16 + it) * 264 + lane * 4] = pk;
    }
    __syncthreads();

    int l15 = lane & 15, q = lane >> 4;
    f32x4 acc[4];
#pragma unroll
    for (int nt = 0; nt < 4; ++nt) acc[nt] = (f32x4){0.f, 0.f, 0.f, 0.f};

    for (int k0 = 0; k0 < 256; k0 += 32) {
        bf16x8 a = *(bf16x8*)&xsh[(w * 16 + l15) * 264 + k0 + q * 8];
#pragma unroll
        for (int nt = 0; nt < 4; ++nt) {
            bf16x8 b = *(const bf16x8*)&WpT_g[(nt * 16 + l15) * 256 + k0 + q * 8];
            acc[nt] = MFMA16(a, b, acc[nt]);
        }
    }

    float mval[4];
#pragma unroll
    for (int reg = 0; reg < 4; ++reg)
        mval[reg] = mask[(size_t)(s0 + w * 16 + q * 4 + reg) * I_DIM + i];

    __syncthreads();
    unsigned short* trsh = xsh;

#pragma unroll
    for (int nt = 0; nt < 4; ++nt) {
        int f = nt * 16 + l15;
        float bv = bias[f];
        unsigned int lo = (unsigned int)f2bf((acc[nt][0] + bv) * mval[0]) |
                          ((unsigned int)f2bf((acc[nt][1] + bv) * mval[1]) << 16);
        unsigned int hi = (unsigned int)f2bf((acc[nt][2] + bv) * mval[2]) |
                          ((unsigned int)f2bf((acc[nt][3] + bv) * mval[3]) << 16);
        uint2 pk; pk.x = lo; pk.y = hi;
        *(uint2*)&trsh[f * 72 + w * 16 + q * 4] = pk;
    }
    __syncthreads();

    {
        int fr = t >> 2, so = (t & 3) * 16;
        unsigned short* dst = ((fr < 32) ? lT : rT) + ((size_t)(i * 32 + (fr & 31)) * 128 + s0 + so);
        *(uint4*)dst = *(uint4*)&trsh[fr * 72 + so];
        *(uint4*)(dst + 8) = *(uint4*)&trsh[fr * 72 + so + 8];
    }
}

// ---------------- FUSED outer + contract, 512 threads (8 waves) ----------------
// Phase 3 streams W2s through a 16 KB double-buffered LDS ring via
// global_load_lds (coalesced, zero-VGPR), per-wave self-service (wave w stages
// its own 16 f-rows), counted vmcnt(1) -- NO barriers in the k-loop.
// Tail fix (R3 bug): at k0==31 the needed DMA is the ONLY outstanding vmem op,
// so vmcnt(1) was a no-op -> stale read. Final iteration peeled with vmcnt(0).
__global__ __launch_bounds__(512, 4) void fused_kernel(const unsigned short* __restrict__ lT,
                                                       const unsigned short* __restrict__ rT,
                                                       const unsigned short* __restrict__ W2s,
                                                       const float* __restrict__ invn,
                                                       const float* __restrict__ out_bias,
                                                       float* __restrict__ out) {
    __shared__ unsigned short sh[32768];   // 64 KB: rT stage (34.8 KB) -> G tile (64 KB)
    __shared__ unsigned short w2b[8192];   // 16 KB: W2s slice ring, 2 x [128 f][32 d]
    char* shb = (char*)sh;
    int t = threadIdx.x;
    int w = t >> 6, lane = t & 63, l15 = lane & 15, q = lane >> 4;
    int bx = blockIdx.x;   // j-block (4 j)
    int by = blockIdx.y;   // i-block (8 i)
    int wm = w >> 1, wn = w & 1;

    // ---- stage rT tile: rows bx*128..+127 (j*32+e), cols s 0..127, pitch 136
    {
        int row = t >> 2, c0 = (t & 3) * 32;
        const unsigned short* rbase = rT + (size_t)(bx * 128 + row) * 128 + c0;
        uint4 v0 = ((const uint4*)rbase)[0];
        uint4 v1 = ((const uint4*)rbase)[1];
        uint4 v2 = ((const uint4*)rbase)[2];
        uint4 v3 = ((const uint4*)rbase)[3];
        *(uint4*)&sh[row * 136 + c0] = v0;
        *(uint4*)&sh[row * 136 + c0 + 8] = v1;
        *(uint4*)&sh[row * 136 + c0 + 16] = v2;
        *(uint4*)&sh[row * 136 + c0 + 24] = v3;
    }

    // phase-1 A fragments for k0=0, issued before the barrier (global, independent)
    const unsigned short* lbase = lT + (size_t)(by * 256 + wm * 64 + l15) * 128 + q * 8;
    bf16x8 a0_ = *(const bf16x8*)(lbase);
    bf16x8 a1_ = *(const bf16x8*)(lbase + 2048);
    bf16x8 a2_ = *(const bf16x8*)(lbase + 4096);
    bf16x8 a3_ = *(const bf16x8*)(lbase + 6144);
    __syncthreads();

    // ---- phase 1: outer GEMM, wave tile 64x64
    f32x4 acc[4][4];
#pragma unroll
    for (int mt = 0; mt < 4; ++mt)
#pragma unroll
        for (int nt = 0; nt < 4; ++nt) acc[mt][nt] = (f32x4){0.f, 0.f, 0.f, 0.f};

#pragma unroll
    for (int k0 = 0; k0 < 4; ++k0) {
        bf16x8 a[4];
        if (k0 == 0) {
            a[0] = a0_; a[1] = a1_; a[2] = a2_; a[3] = a3_;
        } else {
#pragma unroll
            for (int mt = 0; mt < 4; ++mt)
                a[mt] = *(const bf16x8*)(lbase + mt * 2048 + k0 * 32);
        }
#pragma unroll
        for (int nt = 0; nt < 4; ++nt) {
            bf16x8 b = *(bf16x8*)&sh[(wn * 64 + nt * 16 + l15) * 136 + k0 * 32 + q * 8];
#pragma unroll
            for (int mt = 0; mt < 4; ++mt)
                acc[mt][nt] = MFMA16(a[mt], b, acc[mt][nt]);
        }
    }
    __syncthreads();

    // DMA helper: stage slice k0 of W2s (8 KB, all 128 f x 32 d) into ring buf.
#define DMA_W2(K0_)                                                                     \
    __builtin_amdgcn_global_load_lds(                                                   \
        (const __attribute__((address_space(1))) unsigned int*)(const void*)(W2s + (K0_) * 4096 + t * 8), \
        (__attribute__((address_space(3))) unsigned int*)(void*)(&w2b[((K0_) & 1) * 4096 + w * 512]),     \
        16, 0, 0)

    // issue first two slices before phase-2 stores (land during phase 2 + barrier)
    DMA_W2(0);
    DMA_W2(1);

    // ---- phase 2: write G[pair][k] bf16 into LDS (swizzled)
#pragma unroll
    for (int mt = 0; mt < 4; ++mt) {
        int i_loc = wm * 2 + (mt >> 1);
        int dbase2 = ((mt & 1) * 16 + q * 4) * 2;
#pragma unroll
        for (int nt = 0; nt < 4; ++nt) {
            int pair = i_loc * 4 + wn * 2 + (nt >> 1);
            int e = (nt & 1) * 16 + l15;
            unsigned int lo = (unsigned int)f2bf(acc[mt][nt][0]) | ((unsigned int)f2bf(acc[mt][nt][1]) << 16);
            unsigned int hi = (unsigned int)f2bf(acc[mt][nt][2]) | ((unsigned int)f2bf(acc[mt][nt][3]) << 16);
            uint2 pk; pk.x = lo; pk.y = hi;
            *(uint2*)(shb + pair * 2048 + ((e * 64 + dbase2) ^ ((e & 7) << 4) ^ ((pair & 7) << 4))) = pk;
        }
    }
    __syncthreads();   // G visible to all waves; also drains DMA 0/1 (vmcnt(0))

    // ---- phase 3: wave w owns f = w*16 + l15, 32 pairs, K=1024.
    f32x4 acc3[2];
    acc3[0] = (f32x4){0.f, 0.f, 0.f, 0.f};
    acc3[1] = (f32x4){0.f, 0.f, 0.f, 0.f};
    char* gbase0 = shb + l15 * 2048;
    char* gbase1 = shb + (16 + l15) * 2048;
    int sx = (l15 & 7) << 4;
    int brow = (w * 16 + l15) * 32 + q * 8;

#pragma unroll 2
    for (int k0 = 0; k0 < 31; ++k0) {
        asm volatile("s_waitcnt vmcnt(1)" ::: "memory");
        bf16x8 b = *(bf16x8*)&w2b[(k0 & 1) * 4096 + brow];
        int off = ((k0 * 64 + q * 16) ^ ((k0 & 7) << 4)) ^ sx;
        bf16x8 a0 = *(bf16x8*)(gbase0 + off);
        bf16x8 a1 = *(bf16x8*)(gbase1 + off);
        asm volatile("s_waitcnt lgkmcnt(0)" ::: "memory");
        if (k0 < 30) { DMA_W2(k0 + 2); }
        __builtin_amdgcn_sched_barrier(0);
        __builtin_amdgcn_s_setprio(1);
        acc3[0] = MFMA16(a0, b, acc3[0]);
        acc3[1] = MFMA16(a1, b, acc3[1]);
        __builtin_amdgcn_s_setprio(0);
    }
    {   // k0 = 31 peeled: its DMA is the only outstanding op -> must drain fully
        asm volatile("s_waitcnt vmcnt(0)" ::: "memory");
        bf16x8 b = *(bf16x8*)&w2b[(31 & 1) * 4096 + brow];
        int off = ((31 * 64 + q * 16) ^ ((31 & 7) << 4)) ^ sx;
        bf16x8 a0 = *(bf16x8*)(gbase0 + off);
        bf16x8 a1 = *(bf16x8*)(gbase1 + off);
        acc3[0] = MFMA16(a0, b, acc3[0]);
        acc3[1] = MFMA16(a1, b, acc3[1]);
    }
#undef DMA_W2

    // ---- epilogue: direct store from regs
    float bv = out_bias[w * 16 + l15];
#pragma unroll
    for (int mt3 = 0; mt3 < 2; ++mt3) {
#pragma unroll
        for (int reg = 0; reg < 4; ++reg) {
            int pair = mt3 * 16 + q * 4 + reg;
            int gi = by * 8 + (pair >> 2);
            int gj = bx * 4 + (pair & 3);
            float vinv = invn[gi * I_DIM + gj];
            out[((size_t)gi * I_DIM + gj) * 128 + w * 16 + l15] = (acc3[mt3][reg] + bv) * vinv;
        }
    }
}

extern "C" void kernel_launch(void* const* d_in, const int* in_sizes, int n_in,
                              void* d_out, int out_size, void* d_ws, size_t ws_size,
                              hipStream_t stream) {
    const float* node = (const float*)d_in[0];
    const float* mask = (const float*)d_in[1];
    const float* Wp   = (const float*)d_in[2];
    const float* bp   = (const float*)d_in[3];
    const float* W2   = (const float*)d_in[4];
    const float* bo   = (const float*)d_in[5];
    float* out = (float*)d_out;

    char* ws = (char*)d_ws;
    unsigned short* lT  = (unsigned short*)(ws);             // 3,145,728
    unsigned short* rT  = (unsigned short*)(ws + 3145728);   // 3,145,728
    unsigned short* W2s = (unsigned short*)(ws + 6291456);   // 262,144 (slice-major)
    unsigned short* WpT = (unsigned short*)(ws + 6553600);   // 32,768
    float*          inv = (float*)(ws + 6586368);            // 589,824

    hipLaunchKernelGGL(prep_cast, dim3(512), dim3(256), 0, stream, Wp, W2, WpT, W2s);
    hipLaunchKernelGGL(norm_kernel, dim3(24, 24), dim3(256), 0, stream, mask, inv);
    hipLaunchKernelGGL(ln_proj, dim3(768), dim3(256), 0, stream, node, mask, bp, WpT, lT, rT);
    hipLaunchKernelGGL(fused_kernel, dim3(96, 48), dim3(512), 0, stream,
                       lT, rT, W2s, inv, bo, out);
}